// Round 1
// 366.370 us; speedup vs baseline: 1.1958x; 1.1958x over previous
//
#include <hip/hip_runtime.h>

// source (8,64,128,128) f32, flow (8,2,128,128) f32, K=3 -> out (8,64,384,384) f32.
constexpr int Bc = 8, Cc = 64, Hs = 128, Ws = 128, Kk = 3;
constexpr int HO = Kk * Hs;   // 384
constexpr int WO = Kk * Ws;   // 384
constexpr int WG = 768;       // 384 columns x 2 row-bands; 12 waves/wg
constexpr int SP = 132;       // padded LDS row stride (floats). 132*4=528B (16B aligned,
                              // so float4 staging stays legal); 132%32=4 rotates banks
                              // by 4 each row -> kills same-xL/different-yT conflicts.
constexpr int BAND = Hs / 2;  // 64 rows per band

// One workgroup per (b,c): stage the source plane in LDS (padded stride), then all
// bilinear corner gathers hit LDS. WG=768 doubles resident waves/CU (12 -> 24) vs
// the 384-thread version: the kernel was latency-bound (VALUBusy 27%, HBM 21%,
// occupancy 17%), so the lever is TLP, not work reduction.
__global__ __launch_bounds__(WG, 6) void block_extract_lds(
    const float* __restrict__ src, const float* __restrict__ flow,
    float* __restrict__ out)
{
    __shared__ float plane[Hs * SP];   // 67584 B -> still 2 wg/CU (160 KB LDS)

    const int wg  = blockIdx.x;        // = b*64 + c
    const int b   = wg >> 6;
    const int tid = threadIdx.x;

    // ---- stage source plane, coalesced float4, into padded rows (32 float4/row) ----
    const float4* sp4 = (const float4*)(src + (size_t)wg * (Hs * Ws));
    for (int i = tid; i < Hs * Ws / 4; i += WG) {
        const int r = i >> 5, j = i & 31;
        *(float4*)(plane + r * SP + 4 * j) = sp4[i];
    }
    __syncthreads();

    // ---- per-thread constants: one output column X, one 64-row band ----
    const int band = (tid >= 384) ? 1 : 0;
    const int X    = tid - band * 384;      // 0..383
    const int y0   = band * BAND;
    const int y1   = y0 + BAND;

    const int xf = X / 3;
    const float xconst = (float)(X - 2 * xf - 1);   // xf + (X%3 - 1)

    const float* flowy = flow + (size_t)b * 2 * Hs * Ws;
    const float* flowx = flowy + Hs * Ws;
    float* outcol = out + (size_t)wg * (HO * WO) + X;

    float fy = flowy[y0 * Ws + xf];
    float fx = flowx[y0 * Ws + xf];

    for (int yf = y0; yf < y1; ++yf) {
        // prefetch next row's flow (hides L2 latency under this row's compute)
        const int nr = (yf < y1 - 1 ? yf + 1 : yf) * Ws + xf;
        const float fy_n = flowy[nr];
        const float fx_n = flowx[nr];

        // y side: ys_k = (yf + k - 1) + fy, k=0..2 — floor shifts by exactly k
        const float ys0 = (float)(yf - 1) + fy;
        const int   F   = (int)floorf(ys0);

        // x side: shared by the whole k-triple
        const float xs = xconst + fx;
        int xL = (int)floorf(xs);
        xL = min(max(xL, 0), Ws - 1);
        const int   xR  = min(xL + 1, Ws - 1);
        const float dx  = xs - (float)xL;
        const float wx0 = 1.0f - dx;
        const int   cR  = xR - xL;          // 0 or 1

        float* orow = outcol + (size_t)(3 * yf) * WO;
        #pragma unroll
        for (int k = 0; k < 3; ++k) {
            const int   yT  = min(max(F + k, 0), Hs - 1);
            const int   yB  = min(yT + 1, Hs - 1);
            const float dy  = ys0 + (float)k - (float)yT;  // == clamped-ref dy
            const float wy0 = 1.0f - dy;
            const int base = yT * SP + xL;
            const int rB   = (yB - yT) * SP;               // 0 or SP
            const float tl = plane[base];
            const float tr = plane[base + cR];
            const float bl = plane[base + rB];
            const float br = plane[base + rB + cR];
            const float v = (tl * wx0 + tr * dx) * wy0
                          + (bl * wx0 + br * dx) * dy;
            __builtin_nontemporal_store(v, orow + (size_t)k * WO);
        }
        fy = fy_n;
        fx = fx_n;
    }
}

extern "C" void kernel_launch(void* const* d_in, const int* in_sizes, int n_in,
                              void* d_out, int out_size, void* d_ws, size_t ws_size,
                              hipStream_t stream) {
    const float* src  = (const float*)d_in[0];
    const float* flow = (const float*)d_in[1];
    float* out = (float*)d_out;

    dim3 block(WG);
    dim3 grid(Bc * Cc);   // 512 workgroups, one per (b,c) plane; exactly 2/CU
    block_extract_lds<<<grid, block, 0, stream>>>(src, flow, out);
}

// Round 2
// 362.938 us; speedup vs baseline: 1.2071x; 1.0095x over previous
//
#include <hip/hip_runtime.h>

// source (8,64,128,128) f32, flow (8,2,128,128) f32, K=3 -> out (8,64,384,384) f32.
constexpr int Bc = 8, Cc = 64, Hs = 128, Ws = 128, Kk = 3;
constexpr int HO = Kk * Hs;   // 384
constexpr int WO = Kk * Ws;   // 384
constexpr int WG = 768;       // 384 columns x 2 row-bands; 12 waves/wg
constexpr int SP = 132;       // padded LDS row stride (floats). 132*4=528B (16B aligned
                              // for float4 staging); 132%32=4 rotates banks by 4 each
                              // row -> kills same-xL/different-yT conflicts.
constexpr int BAND = Hs / 2;  // 64 rows per band

// One workgroup per (b,c): stage the source plane in LDS with a replicated
// boundary row (128 <- 127) and column (128 <- 127). The replication makes all
// four bilinear corner offsets COMPILE-TIME constants (0, +1, +SP, +SP+1), so
// the compiler merges the 4 ds_read_b32 into 2 ds_read2_b32 — LDS instruction
// issue was ~44us/CU, nearly tied with the 48us HBM write floor.
__global__ __launch_bounds__(WG, 6) void block_extract_lds(
    const float* __restrict__ src, const float* __restrict__ flow,
    float* __restrict__ out)
{
    __shared__ float plane[(Hs + 1) * SP];   // 129*132*4 = 68112 B -> 2 wg/CU

    const int wg  = blockIdx.x;        // = b*64 + c
    const int b   = wg >> 6;
    const int tid = threadIdx.x;

    // ---- stage source plane (+ replicated row 128), coalesced float4 ----
    const float* splane = src + (size_t)wg * (Hs * Ws);
    const float4* sp4 = (const float4*)splane;
    for (int i = tid; i < (Hs + 1) * (Ws / 4); i += WG) {
        const int r = i >> 5, j = i & 31;
        const int sr = (r < Hs) ? r : (Hs - 1);          // row 128 <- row 127
        *(float4*)(plane + r * SP + 4 * j) = sp4[sr * (Ws / 4) + j];
    }
    // ---- replicate column 128 <- column 127 (reads global, no LDS dep) ----
    for (int r = tid; r <= Hs; r += WG) {
        const int sr = (r < Hs) ? r : (Hs - 1);
        plane[r * SP + Ws] = splane[sr * Ws + (Ws - 1)];
    }
    __syncthreads();

    // ---- per-thread constants: one output column X, one 64-row band ----
    const int band = (tid >= 384) ? 1 : 0;
    const int X    = tid - band * 384;      // 0..383
    const int y0   = band * BAND;
    const int y1   = y0 + BAND;

    const int xf = X / 3;
    const float xconst = (float)(X - 2 * xf - 1);   // xf + (X%3 - 1)

    const float* flowy = flow + (size_t)b * 2 * Hs * Ws;
    const float* flowx = flowy + Hs * Ws;
    float* outcol = out + (size_t)wg * (HO * WO) + X;

    float fy = flowy[y0 * Ws + xf];
    float fx = flowx[y0 * Ws + xf];

    for (int yf = y0; yf < y1; ++yf) {
        // prefetch next row's flow (hides L2 latency under this row's compute)
        const int nr = (yf < y1 - 1 ? yf + 1 : yf) * Ws + xf;
        const float fy_n = flowy[nr];
        const float fx_n = flowx[nr];

        // y side: ys_k = (yf + k - 1) + fy, k=0..2 — floor shifts by exactly k
        const float ys0 = (float)(yf - 1) + fy;
        const int   F   = (int)floorf(ys0);

        // x side: shared by the whole k-triple. xL clamped for the address;
        // xR = xL+1 unconditionally (column 128 replicates column 127).
        const float xs = xconst + fx;
        int xL = (int)floorf(xs);
        xL = min(max(xL, 0), Ws - 1);
        const float dx  = xs - (float)xL;
        const float wx0 = 1.0f - dx;

        float* orow = outcol + (size_t)(3 * yf) * WO;
        #pragma unroll
        for (int k = 0; k < 3; ++k) {
            const int   yT  = min(max(F + k, 0), Hs - 1);
            const float dy  = ys0 + (float)k - (float)yT;  // == clamped-ref dy
            const float wy0 = 1.0f - dy;
            // all four offsets constant -> 2x ds_read2_b32
            const float* p = plane + yT * SP + xL;
            const float tl = p[0];
            const float tr = p[1];
            const float bl = p[SP];
            const float br = p[SP + 1];
            const float v = (tl * wx0 + tr * dx) * wy0
                          + (bl * wx0 + br * dx) * dy;
            __builtin_nontemporal_store(v, orow + (size_t)k * WO);
        }
        fy = fy_n;
        fx = fx_n;
    }
}

extern "C" void kernel_launch(void* const* d_in, const int* in_sizes, int n_in,
                              void* d_out, int out_size, void* d_ws, size_t ws_size,
                              hipStream_t stream) {
    const float* src  = (const float*)d_in[0];
    const float* flow = (const float*)d_in[1];
    float* out = (float*)d_out;

    dim3 block(WG);
    dim3 grid(Bc * Cc);   // 512 workgroups, one per (b,c) plane; exactly 2/CU
    block_extract_lds<<<grid, block, 0, stream>>>(src, flow, out);
}

// Round 4
// 357.715 us; speedup vs baseline: 1.2247x; 1.0146x over previous
//
#include <hip/hip_runtime.h>

// source (8,64,128,128) f32, flow (8,2,128,128) f32, K=3 -> out (8,64,384,384) f32.
constexpr int Bc = 8, Cc = 64, Hs = 128, Ws = 128, Kk = 3;
constexpr int HO = Kk * Hs;   // 384
constexpr int WO = Kk * Ws;   // 384
constexpr int WG = 768;       // 384 columns x 2 row-bands; 12 waves/wg
constexpr int SP = 132;       // padded LDS row stride (floats). 132*4=528B (16B aligned
                              // for float4 staging); 132%32=4 rotates banks by 4 each
                              // row -> kills same-xL/different-yT conflicts.
constexpr int BAND = Hs / 2;  // 64 rows per band

// One workgroup per (b,c): stage the source plane in LDS with a replicated
// boundary row (128 <- 127) and column (128 <- 127).
// Fast path (wave-uniform via __all, ~88% of waves): when F=floor(ys0) is
// unclamped, dy/wy0 are IDENTICAL for all 3 k-taps and tap k's bottom row is
// tap k+1's top row -> 4 ds_read2 (rows F..F+3) + 4 row-lerps + 3 vertical
// FMAs replaces 6 ds_read2 + 3x(clamp+addr+bilinear). VALU/iter ~57 -> ~20;
// VALU was the largest pipe term (~73us/CU vs 48us HBM write floor).
__global__ __launch_bounds__(WG, 6) void block_extract_lds(
    const float* __restrict__ src, const float* __restrict__ flow,
    float* __restrict__ out)
{
    __shared__ float plane[(Hs + 1) * SP];   // 129*132*4 = 68112 B -> 2 wg/CU

    const int wg  = blockIdx.x;        // = b*64 + c
    const int b   = wg >> 6;
    const int tid = threadIdx.x;

    // ---- stage source plane (+ replicated row 128), coalesced float4 ----
    const float* splane = src + (size_t)wg * (Hs * Ws);
    const float4* sp4 = (const float4*)splane;
    for (int i = tid; i < (Hs + 1) * (Ws / 4); i += WG) {
        const int r = i >> 5, j = i & 31;
        const int sr = (r < Hs) ? r : (Hs - 1);          // row 128 <- row 127
        *(float4*)(plane + r * SP + 4 * j) = sp4[sr * (Ws / 4) + j];
    }
    // ---- replicate column 128 <- column 127 (reads global, no LDS dep) ----
    for (int r = tid; r <= Hs; r += WG) {
        const int sr = (r < Hs) ? r : (Hs - 1);
        plane[r * SP + Ws] = splane[sr * Ws + (Ws - 1)];
    }
    __syncthreads();

    // ---- per-thread constants: one output column X, one 64-row band ----
    const int band = (tid >= 384) ? 1 : 0;
    const int X    = tid - band * 384;      // 0..383
    const int y0   = band * BAND;
    const int y1   = y0 + BAND;

    const int xf = X / 3;
    const float xconst = (float)(X - 2 * xf - 1);   // xf + (X%3 - 1)

    const float* flowy = flow + (size_t)b * 2 * Hs * Ws;
    const float* flowx = flowy + Hs * Ws;
    float* outcol = out + (size_t)wg * (HO * WO) + X;

    float fy = flowy[y0 * Ws + xf];
    float fx = flowx[y0 * Ws + xf];

    for (int yf = y0; yf < y1; ++yf) {
        // prefetch next row's flow (hides L2 latency under this row's compute)
        const int nr = (yf < y1 - 1 ? yf + 1 : yf) * Ws + xf;
        const float fy_n = flowy[nr];
        const float fx_n = flowx[nr];

        // y side: ys_k = (yf + k - 1) + fy, k=0..2 — floor shifts by exactly k
        const float ys0 = (float)(yf - 1) + fy;
        const float Ff  = floorf(ys0);
        const int   F   = (int)Ff;

        // x side: shared by the whole k-triple. xL clamped for the address;
        // xR = xL+1 unconditionally (column 128 replicates column 127).
        const float xs  = xconst + fx;
        float xLf = floorf(xs);
        xLf = fminf(fmaxf(xLf, 0.0f), 127.0f);
        const int   xL  = (int)xLf;
        const float dx  = xs - xLf;
        const float wx0 = 1.0f - dx;

        float* orow = outcol + (size_t)(3 * yf) * WO;

        if (__all(F >= 0 && F <= 125)) {
            // FAST (wave-uniform): yT(k)=F+k (clamp is identity; F=125 reads
            // row 128 = replicated row 127 = clamped yB). dy shared by all k.
            const float dy  = ys0 - Ff;
            const float wy0 = 1.0f - dy;
            const float* p = plane + F * SP + xL;
            const float r0a = p[0],        r0b = p[1];
            const float r1a = p[SP],       r1b = p[SP + 1];
            const float r2a = p[2 * SP],   r2b = p[2 * SP + 1];
            const float r3a = p[3 * SP],   r3b = p[3 * SP + 1];
            const float h0 = r0a * wx0 + r0b * dx;
            const float h1 = r1a * wx0 + r1b * dx;
            const float h2 = r2a * wx0 + r2b * dx;
            const float h3 = r3a * wx0 + r3b * dx;
            __builtin_nontemporal_store(h0 * wy0 + h1 * dy, orow);
            __builtin_nontemporal_store(h1 * wy0 + h2 * dy, orow + WO);
            __builtin_nontemporal_store(h2 * wy0 + h3 * dy, orow + 2 * WO);
        } else {
            // GENERAL (edge rows / |fy| outliers): exact per-k clamping.
            #pragma unroll
            for (int k = 0; k < 3; ++k) {
                const int   yT  = min(max(F + k, 0), Hs - 1);
                const float dy  = ys0 + (float)k - (float)yT;
                const float wy0 = 1.0f - dy;
                const float* p = plane + yT * SP + xL;
                const float tl = p[0];
                const float tr = p[1];
                const float bl = p[SP];
                const float br = p[SP + 1];
                const float v = (tl * wx0 + tr * dx) * wy0
                              + (bl * wx0 + br * dx) * dy;
                __builtin_nontemporal_store(v, orow + (size_t)k * WO);
            }
        }
        fy = fy_n;
        fx = fx_n;
    }
}

extern "C" void kernel_launch(void* const* d_in, const int* in_sizes, int n_in,
                              void* d_out, int out_size, void* d_ws, size_t ws_size,
                              hipStream_t stream) {
    const float* src  = (const float*)d_in[0];
    const float* flow = (const float*)d_in[1];
    float* out = (float*)d_out;

    dim3 block(WG);
    dim3 grid(Bc * Cc);   // 512 workgroups, one per (b,c) plane; exactly 2/CU
    block_extract_lds<<<grid, block, 0, stream>>>(src, flow, out);
}

// Round 5
// 339.547 us; speedup vs baseline: 1.2902x; 1.0535x over previous
//
#include <hip/hip_runtime.h>

// source (8,64,128,128) f32, flow (8,2,128,128) f32, K=3 -> out (8,64,384,384) f32.
constexpr int Bc = 8, Cc = 64, Hs = 128, Ws = 128, Kk = 3;
constexpr int HO = Kk * Hs;   // 384
constexpr int WO = Kk * Ws;   // 384
constexpr int WG = 768;       // 384 columns x 2 row-bands; 12 waves/wg
constexpr int SP = 136;       // LDS row stride (floats); 136%32=8 rotates banks 8/row,
                              // 136*4=544B keeps float4 row starts 16B-aligned.
constexpr int ROWS = 133;     // r_mem = src_row + 2: virtual rows -2..130
constexpr int BAND = Hs / 2;  // 64 rows per band
// Column layout: c_mem = src_col + 4. Guard col -1 at c_mem 3, col 128 at c_mem 132.
// LDS = 133*136*4 = 72352 B -> 2 wg/CU.

// BRANCHLESS inner loop: the R4 profile showed the wave-uniform fast/slow branch
// was the real cost — it blocks cross-iteration software pipelining, leaving each
// iteration serialized on ~120cy LDS latency. We remove ALL clamped-tap special
// cases by staging guard rows/cols:
//   bottom guards COLLINEAR:  row(-c) = (1+c)*row0 - c*row1  (c=1,2), col(-1) likewise
//   top guards REPLICATED:    rows 128..130 = row127, col 128 = col127
// With F' = clamp(floor(ys0),-2,127), x' = clamp(floor(xs),-1,127) and UNCLAMPED
// d = ys0-F', dx = xs-x', the shared-d 4-row lerp is exact everywhere:
//   interior -> real bilinear; below-edge -> lerp of collinear guards == reference's
//   negative-dy extrapolation; above-edge -> lerp of identical rows == clamped value.
__global__ __launch_bounds__(WG, 6) void block_extract_lds(
    const float* __restrict__ src, const float* __restrict__ flow,
    float* __restrict__ out)
{
    __shared__ float plane[ROWS * SP];

    const int wg  = blockIdx.x;        // = b*64 + c
    const int b   = wg >> 6;
    const int tid = threadIdx.x;

    const float* splane = src + (size_t)wg * (Hs * Ws);

    // ---- stage core rows 0..127 into r_mem 2..129, c_mem 4..131 (float4) ----
    const float4* sp4 = (const float4*)splane;
    for (int i = tid; i < Hs * (Ws / 4); i += WG) {
        const int r = i >> 5, j = i & 31;
        *(float4*)(plane + (r + 2) * SP + 4 + 4 * j) = sp4[i];
    }
    // ---- column guards for core rows: c_mem 3 (extrap) and 132 (replicate) ----
    for (int r = tid; r < Hs; r += WG) {
        const float a = splane[r * Ws];
        const float b2 = splane[r * Ws + 1];
        plane[(r + 2) * SP + 3]   = 2.0f * a - b2;          // col -1
        plane[(r + 2) * SP + 132] = splane[r * Ws + 127];   // col 128
    }
    // ---- guard rows: r_mem 0,1 (collinear below), 130..132 (replicate row127),
    //      spanning c_mem 3..132 (virtual cols -1..128); computed from global ----
    for (int t = tid; t < 5 * 130; t += WG) {
        const int g  = t / 130;        // 0,1 -> bottom; 2,3,4 -> top
        const int cc = t % 130;        // c_mem = cc + 3, virtual col c = cc - 1
        const int c  = cc - 1;
        float v;
        int rmem;
        if (g < 2) {
            const float e0 = (c == -1) ? 2.0f * splane[0] - splane[1]
                           : (c == 128) ? splane[127] : splane[c];
            const float e1 = (c == -1) ? 2.0f * splane[Ws] - splane[Ws + 1]
                           : (c == 128) ? splane[Ws + 127] : splane[Ws + c];
            v = (g == 0) ? 3.0f * e0 - 2.0f * e1    // virtual row -2
                         : 2.0f * e0 - e1;          // virtual row -1
            rmem = g;
        } else {
            const float* r127 = splane + 127 * Ws;
            v = (c == -1) ? 2.0f * r127[0] - r127[1]
              : (c == 128) ? r127[127] : r127[c];
            rmem = 128 + g;                          // 130,131,132
        }
        plane[rmem * SP + cc + 3] = v;
    }
    __syncthreads();

    // ---- per-thread constants: one output column X, one 64-row band ----
    const int band = (tid >= 384) ? 1 : 0;
    const int X    = tid - band * 384;      // 0..383
    const int y0   = band * BAND;
    const int y1   = y0 + BAND;

    const int xf = X / 3;
    const float xconst = (float)(X - 2 * xf - 1);   // xf + (X%3 - 1)

    const float* flowy = flow + (size_t)b * 2 * Hs * Ws;
    const float* flowx = flowy + Hs * Ws;
    float* orow = out + (size_t)wg * (HO * WO) + X + (size_t)(3 * y0) * WO;

    float fy = flowy[y0 * Ws + xf];
    float fx = flowx[y0 * Ws + xf];

    #pragma unroll 2
    for (int yf = y0; yf < y1; ++yf) {
        // prefetch next row's flow (hides L2 latency under this row's compute)
        const int nr = (yf < y1 - 1 ? yf + 1 : yf) * Ws + xf;
        const float fy_n = flowy[nr];
        const float fx_n = flowx[nr];

        // y side: shared by all 3 k-taps; clamp into guard range, d UNclamped
        const float ys0 = (float)(yf - 1) + fy;
        float Ff = floorf(ys0);
        Ff = fminf(fmaxf(Ff, -2.0f), 127.0f);
        const float d  = ys0 - Ff;
        const float w0 = 1.0f - d;

        // x side: clamp into guard range, dx UNclamped
        const float xs = xconst + fx;
        float xLf = floorf(xs);
        xLf = fminf(fmaxf(xLf, -1.0f), 127.0f);
        const float dx = xs - xLf;
        const float wx = 1.0f - dx;

        const float* p = plane + ((int)Ff + 2) * SP + ((int)xLf + 4);
        const float r0a = p[0],  r0b = p[1];
        const float r1a = p[SP], r1b = p[SP + 1];
        const float* q = p + 2 * SP;                 // ds offset imm <= 255 dwords
        const float r2a = q[0],  r2b = q[1];
        const float r3a = q[SP], r3b = q[SP + 1];

        const float h0 = r0a * wx + r0b * dx;
        const float h1 = r1a * wx + r1b * dx;
        const float h2 = r2a * wx + r2b * dx;
        const float h3 = r3a * wx + r3b * dx;

        __builtin_nontemporal_store(h0 * w0 + h1 * d, orow);
        __builtin_nontemporal_store(h1 * w0 + h2 * d, orow + WO);
        __builtin_nontemporal_store(h2 * w0 + h3 * d, orow + 2 * WO);

        orow += 3 * WO;
        fy = fy_n;
        fx = fx_n;
    }
}

extern "C" void kernel_launch(void* const* d_in, const int* in_sizes, int n_in,
                              void* d_out, int out_size, void* d_ws, size_t ws_size,
                              hipStream_t stream) {
    const float* src  = (const float*)d_in[0];
    const float* flow = (const float*)d_in[1];
    float* out = (float*)d_out;

    dim3 block(WG);
    dim3 grid(Bc * Cc);   // 512 workgroups, one per (b,c) plane; exactly 2/CU
    block_extract_lds<<<grid, block, 0, stream>>>(src, flow, out);
}

// Round 6
// 322.524 us; speedup vs baseline: 1.3583x; 1.0528x over previous
//
#include <hip/hip_runtime.h>

// source (8,64,128,128) f32, flow (8,2,128,128) f32, K=3 -> out (8,64,384,384) f32.
constexpr int Bc = 8, Cc = 64, Hs = 128, Ws = 128, Kk = 3;
constexpr int HO = Kk * Hs;   // 384
constexpr int WO = Kk * Ws;   // 384
constexpr int WG = 768;       // 384 columns x 2 row-bands; 12 waves/wg
constexpr int SP = 136;       // LDS row stride (floats); 136%32=8 rotates banks 8/row,
                              // 136*4=544B keeps float4 row starts 16B-aligned.
constexpr int ROWS = 133;     // r_mem = src_row + 2: virtual rows -2..130
constexpr int BAND = Hs / 2;  // 64 rows per band
// Column layout: c_mem = src_col + 4. Guard col -1 at c_mem 3, col 128 at c_mem 132.
// LDS = 133*136*4 = 72352 B -> 2 wg/CU.

// Branchless guard-row scheme (see R5): bottom guards collinear, top guards
// replicated; shared-d 4-row lerp is exact for every clamp case.
// R6 change: the flow load was prefetched only 1 iteration (~100cy) ahead but
// costs ~200-225cy from L2 -> ~100cy exposed stall per iteration on the loop's
// critical path (the remaining ~80K cy/CU of slack vs the 48us write floor).
// Restructure into groups of 4 rows with a 4-deep register FIFO: issue next
// group's 8 flow loads first (distance ~400+cy), then 4 fully-unrolled
// independent iterations (16 ds_read2 + 12 stores in flight per wave).
__global__ __launch_bounds__(WG, 6) void block_extract_lds(
    const float* __restrict__ src, const float* __restrict__ flow,
    float* __restrict__ out)
{
    __shared__ float plane[ROWS * SP];

    const int wg  = blockIdx.x;        // = b*64 + c
    const int b   = wg >> 6;
    const int tid = threadIdx.x;

    const float* splane = src + (size_t)wg * (Hs * Ws);

    // ---- stage core rows 0..127 into r_mem 2..129, c_mem 4..131 (float4) ----
    const float4* sp4 = (const float4*)splane;
    for (int i = tid; i < Hs * (Ws / 4); i += WG) {
        const int r = i >> 5, j = i & 31;
        *(float4*)(plane + (r + 2) * SP + 4 + 4 * j) = sp4[i];
    }
    // ---- column guards for core rows: c_mem 3 (extrap) and 132 (replicate) ----
    for (int r = tid; r < Hs; r += WG) {
        const float a = splane[r * Ws];
        const float b2 = splane[r * Ws + 1];
        plane[(r + 2) * SP + 3]   = 2.0f * a - b2;          // col -1
        plane[(r + 2) * SP + 132] = splane[r * Ws + 127];   // col 128
    }
    // ---- guard rows: r_mem 0,1 (collinear below), 130..132 (replicate row127),
    //      spanning c_mem 3..132 (virtual cols -1..128); computed from global ----
    for (int t = tid; t < 5 * 130; t += WG) {
        const int g  = t / 130;        // 0,1 -> bottom; 2,3,4 -> top
        const int cc = t % 130;        // c_mem = cc + 3, virtual col c = cc - 1
        const int c  = cc - 1;
        float v;
        int rmem;
        if (g < 2) {
            const float e0 = (c == -1) ? 2.0f * splane[0] - splane[1]
                           : (c == 128) ? splane[127] : splane[c];
            const float e1 = (c == -1) ? 2.0f * splane[Ws] - splane[Ws + 1]
                           : (c == 128) ? splane[Ws + 127] : splane[Ws + c];
            v = (g == 0) ? 3.0f * e0 - 2.0f * e1    // virtual row -2
                         : 2.0f * e0 - e1;          // virtual row -1
            rmem = g;
        } else {
            const float* r127 = splane + 127 * Ws;
            v = (c == -1) ? 2.0f * r127[0] - r127[1]
              : (c == 128) ? r127[127] : r127[c];
            rmem = 128 + g;                          // 130,131,132
        }
        plane[rmem * SP + cc + 3] = v;
    }
    __syncthreads();

    // ---- per-thread constants: one output column X, one 64-row band ----
    const int band = (tid >= 384) ? 1 : 0;
    const int X    = tid - band * 384;      // 0..383
    const int y0   = band * BAND;

    const int xf = X / 3;
    const float xconst = (float)(X - 2 * xf - 1);   // xf + (X%3 - 1)

    const float* flowy = flow + (size_t)b * 2 * Hs * Ws;
    const float* flowx = flowy + Hs * Ws;
    const float* fybase = flowy + xf;
    const float* fxbase = flowx + xf;
    float* orow = out + (size_t)wg * (HO * WO) + X + (size_t)(3 * y0) * WO;

    // 4-deep flow FIFO (all indices compile-time via full unroll)
    float fyv[4], fxv[4];
    #pragma unroll
    for (int j = 0; j < 4; ++j) {
        fyv[j] = fybase[(y0 + j) * Ws];
        fxv[j] = fxbase[(y0 + j) * Ws];
    }

    constexpr int NG = BAND / 4;   // 16 groups of 4 rows
    for (int g = 0; g < NG; ++g) {
        const int yf0 = y0 + 4 * g;

        // prefetch next group's flow (~400+cy ahead); last group reloads
        // already-cached rows (values unused)
        const int pr = (g < NG - 1) ? (yf0 + 4) : y0;
        float fyn[4], fxn[4];
        #pragma unroll
        for (int j = 0; j < 4; ++j) {
            fyn[j] = fybase[(pr + j) * Ws];
            fxn[j] = fxbase[(pr + j) * Ws];
        }

        #pragma unroll
        for (int j = 0; j < 4; ++j) {
            // y side: shared by all 3 k-taps; clamp into guard range, d UNclamped
            const float ys0 = (float)(yf0 + j - 1) + fyv[j];
            float Ff = floorf(ys0);
            Ff = fminf(fmaxf(Ff, -2.0f), 127.0f);
            const float d  = ys0 - Ff;
            const float w0 = 1.0f - d;

            // x side: clamp into guard range, dx UNclamped
            const float xs = xconst + fxv[j];
            float xLf = floorf(xs);
            xLf = fminf(fmaxf(xLf, -1.0f), 127.0f);
            const float dx = xs - xLf;
            const float wx = 1.0f - dx;

            const float* p = plane + ((int)Ff + 2) * SP + ((int)xLf + 4);
            const float r0a = p[0],  r0b = p[1];
            const float r1a = p[SP], r1b = p[SP + 1];
            const float* q = p + 2 * SP;             // keep ds imm offsets small
            const float r2a = q[0],  r2b = q[1];
            const float r3a = q[SP], r3b = q[SP + 1];

            const float h0 = r0a * wx + r0b * dx;
            const float h1 = r1a * wx + r1b * dx;
            const float h2 = r2a * wx + r2b * dx;
            const float h3 = r3a * wx + r3b * dx;

            float* o = orow + (size_t)(3 * j) * WO;
            __builtin_nontemporal_store(h0 * w0 + h1 * d, o);
            __builtin_nontemporal_store(h1 * w0 + h2 * d, o + WO);
            __builtin_nontemporal_store(h2 * w0 + h3 * d, o + 2 * WO);
        }

        #pragma unroll
        for (int j = 0; j < 4; ++j) { fyv[j] = fyn[j]; fxv[j] = fxn[j]; }
        orow += 12 * WO;
    }
}

extern "C" void kernel_launch(void* const* d_in, const int* in_sizes, int n_in,
                              void* d_out, int out_size, void* d_ws, size_t ws_size,
                              hipStream_t stream) {
    const float* src  = (const float*)d_in[0];
    const float* flow = (const float*)d_in[1];
    float* out = (float*)d_out;

    dim3 block(WG);
    dim3 grid(Bc * Cc);   // 512 workgroups, one per (b,c) plane; exactly 2/CU
    block_extract_lds<<<grid, block, 0, stream>>>(src, flow, out);
}